// Round 17
// baseline (189.519 us; speedup 1.0000x reference)
//
#include <hip/hip_runtime.h>
#include <math.h>

#define D_MODEL 1024
#define NHEAD   16
#define DKH     64
#define SEQ     2048
#define BATCH   2
#define TOK     (BATCH*SEQ)   // 4096

typedef short s16x8 __attribute__((ext_vector_type(8)));
typedef float f32x4 __attribute__((ext_vector_type(4)));
typedef float f32x16 __attribute__((ext_vector_type(16)));
typedef unsigned short ushort_t;

__device__ inline unsigned short f2bf(float f) {
    union { float f; unsigned u; } v; v.f = f;
    unsigned r = v.u + 0x7FFFu + ((v.u >> 16) & 1u);   // RNE
    return (unsigned short)(r >> 16);
}
__device__ inline float bf2f(ushort_t h) {
    union { unsigned u; float f; } v; v.u = (unsigned)h << 16;
    return v.f;
}
__device__ inline unsigned cvt_pk_bf16(float a, float b) {  // low16=bf16(a), high16=bf16(b)
    unsigned r;
    asm("v_cvt_pk_bf16_f32 %0, %1, %2" : "=v"(r) : "v"(a), "v"(b));
    return r;
}
__device__ inline void gload16(const void* g, void* l) {
    __builtin_amdgcn_global_load_lds(
        (const __attribute__((address_space(1))) void*)g,
        (__attribute__((address_space(3))) void*)l, 16, 0, 0);
}
__device__ inline f32x16 zero16() {
    f32x16 v;
#pragma unroll
    for (int i = 0; i < 16; ++i) v[i] = 0.f;
    return v;
}

// ---------------------------------------------------------------------------
// fp32->bf16: q,k,v and Wq,Wk,Wv plain; Wo as hi+lo split; mask -> float bias.
// ---------------------------------------------------------------------------
__global__ __launch_bounds__(256) void convert_all(
    const float* __restrict__ q, const float* __restrict__ k,
    const float* __restrict__ v,
    const float* __restrict__ Wq, const float* __restrict__ Wk,
    const float* __restrict__ Wv, const float* __restrict__ Wo,
    const int* __restrict__ mask,
    ushort_t* __restrict__ qb, ushort_t* __restrict__ kb,
    ushort_t* __restrict__ vb,
    ushort_t* __restrict__ Wqb, ushort_t* __restrict__ Wkb,
    ushort_t* __restrict__ Wvb, ushort_t* __restrict__ Wohi,
    ushort_t* __restrict__ Wolo, float* __restrict__ mb)
{
    const int ACT4 = TOK * D_MODEL / 4;       // 1048576
    const int W4   = D_MODEL * D_MODEL / 4;   // 262144
    const int total = 3 * ACT4 + 4 * W4 + TOK / 4;
    for (int u = blockIdx.x * 256 + threadIdx.x; u < total; u += gridDim.x * 256) {
        if (u < 3 * ACT4) {
            int which = u / ACT4, off = u - which * ACT4;
            const float* src = which == 0 ? q : which == 1 ? k : v;
            ushort_t*    dst = which == 0 ? qb : which == 1 ? kb : vb;
            float4 f = ((const float4*)src)[off];
            uint2 o;
            o.x = cvt_pk_bf16(f.x, f.y);
            o.y = cvt_pk_bf16(f.z, f.w);
            ((uint2*)dst)[off] = o;
        } else if (u < 3 * ACT4 + 3 * W4) {
            int uu = u - 3 * ACT4;
            int which = uu / W4, off = uu - which * W4;
            const float* src = which == 0 ? Wq : which == 1 ? Wk : Wv;
            ushort_t*    dst = which == 0 ? Wqb : which == 1 ? Wkb : Wvb;
            float4 f = ((const float4*)src)[off];
            uint2 o;
            o.x = cvt_pk_bf16(f.x, f.y);
            o.y = cvt_pk_bf16(f.z, f.w);
            ((uint2*)dst)[off] = o;
        } else if (u < 3 * ACT4 + 4 * W4) {
            int off = u - (3 * ACT4 + 3 * W4);
            float4 f = ((const float4*)Wo)[off];
            ushort_t h0 = f2bf(f.x), h1 = f2bf(f.y), h2 = f2bf(f.z), h3 = f2bf(f.w);
            uint2 hw;
            hw.x = (unsigned)h0 | ((unsigned)h1 << 16);
            hw.y = (unsigned)h2 | ((unsigned)h3 << 16);
            ((uint2*)Wohi)[off] = hw;
            uint2 lw;
            lw.x = cvt_pk_bf16(f.x - bf2f(h0), f.y - bf2f(h1));
            lw.y = cvt_pk_bf16(f.z - bf2f(h2), f.w - bf2f(h3));
            ((uint2*)Wolo)[off] = lw;
        } else {
            int off = u - (3 * ACT4 + 4 * W4);
            int4 m = ((const int4*)mask)[off];
            float4 f;
            f.x = m.x ? 0.f : -1e9f;
            f.y = m.y ? 0.f : -1e9f;
            f.z = m.z ? 0.f : -1e9f;
            f.w = m.w ? 0.f : -1e9f;
            ((float4*)mb)[off] = f;
        }
    }
}

// ---------------------------------------------------------------------------
// Fused Q/K/V projection GEMM, pure bf16 (m97 structure): blockIdx.z = {q,k,v}.
// BM=128 BN=128 BK=32, 256 thr, wave-tile 64x64, global_load_lds staging,
// chunked XCD swizzle. z<2 -> row-major bf16; z==2 -> [b][h][d][s].
// ---------------------------------------------------------------------------
__global__ __launch_bounds__(256) void gemm_qkv(
    const ushort_t* __restrict__ qb, const ushort_t* __restrict__ kb,
    const ushort_t* __restrict__ vb,
    const ushort_t* __restrict__ Wqb, const ushort_t* __restrict__ Wkb,
    const ushort_t* __restrict__ Wvb,
    const float* __restrict__ bqp, const float* __restrict__ bkp,
    const float* __restrict__ bvp,
    ushort_t* __restrict__ Qb, ushort_t* __restrict__ Kb,
    ushort_t* __restrict__ Vtb)
{
    __shared__ __align__(16) char pool[64 * 136 * 2];   // 16KB staging / 17KB epi
    ushort_t* As = (ushort_t*)pool;                     // [128][32]
    ushort_t* Ws = As + 128 * 32;                       // [128][32]

    const int z = blockIdx.z;
    const ushort_t* Ain  = z == 0 ? qb : z == 1 ? kb : vb;
    const ushort_t* Wptr = z == 0 ? Wqb : z == 1 ? Wkb : Wvb;
    const float*    bias = z == 0 ? bqp : z == 1 ? bkp : bvp;

    const int hwid = blockIdx.x + 8 * blockIdx.y;       // 0..255, XCD = hwid%8
    const int work = (hwid & 7) * 32 + (hwid >> 3);
    const int m0 = (work >> 3) * 128;
    const int n0 = (work & 7) * 128;

    const int t = threadIdx.x;
    const int w = t >> 6, lane = t & 63, l15 = lane & 15, l4 = lane >> 4;
    const int wr = w >> 1, wc = w & 1;

    f32x4 acc[4][4];
#pragma unroll
    for (int m = 0; m < 4; ++m)
#pragma unroll
        for (int n = 0; n < 4; ++n) acc[m][n] = (f32x4){0.f, 0.f, 0.f, 0.f};

    const ushort_t* Ag = Ain  + (size_t)(m0 + (t >> 2)) * D_MODEL + (t & 3) * 8;
    const ushort_t* Wg = Wptr + (size_t)(n0 + (t >> 2)) * D_MODEL + (t & 3) * 8;
    ushort_t* AsW = As + w * 512;
    ushort_t* WsW = Ws + w * 512;

    for (int k0 = 0; k0 < D_MODEL; k0 += 32) {
        __syncthreads();
        gload16(Ag + k0, AsW);
        gload16(Ag + (size_t)64 * D_MODEL + k0, AsW + 2048);
        gload16(Wg + k0, WsW);
        gload16(Wg + (size_t)64 * D_MODEL + k0, WsW + 2048);
        __syncthreads();

        s16x8 af[4], bfr[4];
#pragma unroll
        for (int m = 0; m < 4; ++m)
            af[m] = *(const s16x8*)&As[(wr * 64 + m * 16 + l15) * 32 + l4 * 8];
#pragma unroll
        for (int n = 0; n < 4; ++n)
            bfr[n] = *(const s16x8*)&Ws[(wc * 64 + n * 16 + l15) * 32 + l4 * 8];
#pragma unroll
        for (int m = 0; m < 4; ++m)
#pragma unroll
            for (int n = 0; n < 4; ++n)
                acc[m][n] = __builtin_amdgcn_mfma_f32_16x16x32_bf16(af[m], bfr[n], acc[m][n], 0, 0, 0);
    }

    if (z == 2) {   // transposed per-head epilogue -> Vtb[b][h][d][s], 2 halves
        ushort_t* Ct = (ushort_t*)pool;   // [64][136]
        const int h0 = n0 >> 6;
        const int bb = m0 >> 11;
        const int s0 = m0 & (SEQ - 1);
#pragma unroll
        for (int hh = 0; hh < 2; ++hh) {
            __syncthreads();
            if (wc == hh) {
#pragma unroll
                for (int n = 0; n < 4; ++n) {
                    const int nl = n * 16 + l15;
                    const float bv = bias[n0 + hh * 64 + nl];
#pragma unroll
                    for (int m = 0; m < 4; ++m) {
                        const int ml = wr * 64 + m * 16 + l4 * 4;
#pragma unroll
                        for (int r = 0; r < 4; ++r)
                            Ct[nl * 136 + ml + r] = f2bf(acc[m][n][r] + bv);
                    }
                }
            }
            __syncthreads();
            const int dl = t >> 2;
            ushort_t* dst = Vtb + (((size_t)bb * NHEAD + h0 + hh) * DKH + dl) * SEQ + s0;
#pragma unroll
            for (int c = 0; c < 4; ++c) {
                int chk = (t & 3) + c * 4;
                *(uint4*)&dst[chk * 8] = *(const uint4*)&Ct[dl * 136 + chk * 8];
            }
        }
    } else {
        ushort_t* Cout = z == 0 ? Qb : Kb;
#pragma unroll
        for (int n = 0; n < 4; ++n) {
            const int col = n0 + wc * 64 + n * 16 + l15;
            const float bv = bias[col];
#pragma unroll
            for (int m = 0; m < 4; ++m) {
                const int row = m0 + wr * 64 + m * 16 + l4 * 4;
#pragma unroll
                for (int r = 0; r < 4; ++r)
                    Cout[(size_t)(row + r) * D_MODEL + col] = f2bf(acc[m][n][r] + bv);
            }
        }
    }
}

// ---------------------------------------------------------------------------
// Output projection GEMM: C[TOK][D] fp32 = Ctx_bf16 @ (Wohi + Wolo)^T + bias.
// BM=128 BN=64 BK=32, 256 thr, global_load_lds staging + chunked XCD swizzle.
// ---------------------------------------------------------------------------
__global__ __launch_bounds__(256) void gemm_out(
    const ushort_t* __restrict__ Ain, const ushort_t* __restrict__ Wptr,
    const ushort_t* __restrict__ W2ptr, const float* __restrict__ bias,
    float* __restrict__ Cout)
{
    __shared__ ushort_t As[128 * 32];
    __shared__ ushort_t Ws[64 * 32];
    __shared__ ushort_t Ws2[64 * 32];

    const int hwid = blockIdx.x + 16 * blockIdx.y;
    const int work = (hwid & 7) * 64 + (hwid >> 3);
    const int m0 = (work >> 4) * 128;
    const int n0 = (work & 15) * 64;

    const int t = threadIdx.x;
    const int w = t >> 6, lane = t & 63, l15 = lane & 15, l4 = lane >> 4;
    const int wr = w >> 1, wc = w & 1;

    f32x4 acc[4][2];
#pragma unroll
    for (int m = 0; m < 4; ++m)
#pragma unroll
        for (int n = 0; n < 2; ++n) acc[m][n] = (f32x4){0.f, 0.f, 0.f, 0.f};

    const ushort_t* Ag  = Ain   + (size_t)(m0 + (t >> 2)) * D_MODEL + (t & 3) * 8;
    const ushort_t* Wg  = Wptr  + (size_t)(n0 + (t >> 2)) * D_MODEL + (t & 3) * 8;
    const ushort_t* W2g = W2ptr + (size_t)(n0 + (t >> 2)) * D_MODEL + (t & 3) * 8;
    ushort_t* AsW = As + w * 512;
    ushort_t* WsW = Ws + w * 512;
    ushort_t* Ws2W = Ws2 + w * 512;

    for (int k0 = 0; k0 < D_MODEL; k0 += 32) {
        __syncthreads();
        gload16(Ag + k0, AsW);
        gload16(Ag + (size_t)64 * D_MODEL + k0, AsW + 2048);
        gload16(Wg + k0, WsW);
        gload16(W2g + k0, Ws2W);
        __syncthreads();

        s16x8 af[4], bfr[2], bfr2[2];
#pragma unroll
        for (int m = 0; m < 4; ++m)
            af[m] = *(const s16x8*)&As[(wr * 64 + m * 16 + l15) * 32 + l4 * 8];
#pragma unroll
        for (int n = 0; n < 2; ++n) {
            bfr[n]  = *(const s16x8*)&Ws[(wc * 32 + n * 16 + l15) * 32 + l4 * 8];
            bfr2[n] = *(const s16x8*)&Ws2[(wc * 32 + n * 16 + l15) * 32 + l4 * 8];
        }
#pragma unroll
        for (int m = 0; m < 4; ++m)
#pragma unroll
            for (int n = 0; n < 2; ++n) {
                acc[m][n] = __builtin_amdgcn_mfma_f32_16x16x32_bf16(af[m], bfr[n],  acc[m][n], 0, 0, 0);
                acc[m][n] = __builtin_amdgcn_mfma_f32_16x16x32_bf16(af[m], bfr2[n], acc[m][n], 0, 0, 0);
            }
    }

#pragma unroll
    for (int n = 0; n < 2; ++n) {
        const int col = n0 + wc * 32 + n * 16 + l15;
        const float bv = bias[col];
#pragma unroll
        for (int m = 0; m < 4; ++m) {
            const int row = m0 + wr * 64 + m * 16 + l4 * 4;
#pragma unroll
            for (int r = 0; r < 4; ++r)
                Cout[(size_t)(row + r) * D_MODEL + col] = acc[m][n][r] + bv;
        }
    }
}

// ---------------------------------------------------------------------------
// Flash attention v7: flash5 skeleton (PASSED round 15) with KVB 64 -> 128.
// SAME 2-barrier staging skeleton; the per-64-key compute body is the exact
// flash5 body run twice per tile (half = 0,1) with no extra syncthreads
// (Ps wave-private; K/V read-only within a tile). Each half uses an exact
// flash5-geometry [64][72] LDS sub-tile (measured conflict-free). Barriers
// per block halve: 64 -> 32. Prefetch regs 16 -> 32 VGPR (~100 total).
// Arithmetic and key order identical to flash5 -> bit-identical output.
// ---------------------------------------------------------------------------
__global__ __launch_bounds__(256) void flash7(
    const ushort_t* __restrict__ Q, const ushort_t* __restrict__ K,
    const ushort_t* __restrict__ Vt, const float* __restrict__ mb,
    ushort_t* __restrict__ Ctx)
{
    __shared__ ushort_t Ks[2][64 * 72];   // [key-half][key-row][d]
    __shared__ ushort_t Vs[2][64 * 72];   // [key-half][d-row][key]
    __shared__ ushort_t Ps[128 * 72];

    const int t = threadIdx.x;
    const int w = t >> 6, lane = t & 63;
    const int l31 = lane & 31, lh = lane >> 5;
    const int q0 = blockIdx.y * 128;
    const int bh = blockIdx.x, b = bh >> 4, h = bh & 15;

    // Q fragments: A-operand rows = q0 + w*32 + l31, k-chunk = ks*16 + lh*8
    s16x8 qf[4];
    {
        const ushort_t* qp = Q + ((size_t)b * SEQ + q0 + w * 32 + l31) * D_MODEL + h * DKH + lh * 8;
#pragma unroll
        for (int ks = 0; ks < 4; ++ks)
            qf[ks] = *(const s16x8*)(qp + ks * 16);
    }

    f32x16 oacc0 = zero16(), oacc1 = zero16();
    float lpart[16];
#pragma unroll
    for (int i = 0; i < 16; ++i) lpart[i] = 0.f;

    const int ch   = t & 7;
    const int row0 = t >> 3;
    const ushort_t* Kg = K  + ((size_t)b * SEQ) * D_MODEL + h * DKH + ch * 8;
    const ushort_t* Vg = Vt + ((size_t)bh * DKH) * SEQ + ch * 8;

    const float CSC = 0.18033688011112042f;   // 0.125 * log2(e)
    const float* mbp = mb + b * SEQ;
    const int prow = w * 32;                  // wave's private Ps row base

    // prefetch tile 0 (128 keys)
    uint4 kr[4], vr[4];
    kr[0] = *(const uint4*)&Kg[(size_t)row0 * D_MODEL];
    kr[1] = *(const uint4*)&Kg[(size_t)(row0 + 32) * D_MODEL];
    kr[2] = *(const uint4*)&Kg[(size_t)(64 + row0) * D_MODEL];
    kr[3] = *(const uint4*)&Kg[(size_t)(64 + row0 + 32) * D_MODEL];
    vr[0] = *(const uint4*)&Vg[(size_t)row0 * SEQ];
    vr[1] = *(const uint4*)&Vg[(size_t)(row0 + 32) * SEQ];
    vr[2] = *(const uint4*)&Vg[(size_t)row0 * SEQ + 64];
    vr[3] = *(const uint4*)&Vg[(size_t)(row0 + 32) * SEQ + 64];

    const int NT = SEQ / 128;   // 16 tiles
    for (int tt = 0; tt < NT; ++tt) {
        __syncthreads();   // prior compute done with LDS
        *(uint4*)&Ks[0][row0 * 72 + ch * 8]        = kr[0];
        *(uint4*)&Ks[0][(row0 + 32) * 72 + ch * 8] = kr[1];
        *(uint4*)&Ks[1][row0 * 72 + ch * 8]        = kr[2];
        *(uint4*)&Ks[1][(row0 + 32) * 72 + ch * 8] = kr[3];
        *(uint4*)&Vs[0][row0 * 72 + ch * 8]        = vr[0];
        *(uint4*)&Vs[0][(row0 + 32) * 72 + ch * 8] = vr[1];
        *(uint4*)&Vs[1][row0 * 72 + ch * 8]        = vr[2];
        *(uint4*)&Vs[1][(row0 + 32) * 72 + ch * 8] = vr[3];
        __syncthreads();   // staged visible
        if (tt + 1 < NT) {   // prefetch next 128-key tile (hides under compute)
            const int kn = (tt + 1) * 128;
            kr[0] = *(const uint4*)&Kg[(size_t)(kn + row0) * D_MODEL];
            kr[1] = *(const uint4*)&Kg[(size_t)(kn + row0 + 32) * D_MODEL];
            kr[2] = *(const uint4*)&Kg[(size_t)(kn + 64 + row0) * D_MODEL];
            kr[3] = *(const uint4*)&Kg[(size_t)(kn + 64 + row0 + 32) * D_MODEL];
            vr[0] = *(const uint4*)&Vg[(size_t)row0 * SEQ + kn];
            vr[1] = *(const uint4*)&Vg[(size_t)(row0 + 32) * SEQ + kn];
            vr[2] = *(const uint4*)&Vg[(size_t)row0 * SEQ + kn + 64];
            vr[3] = *(const uint4*)&Vg[(size_t)(row0 + 32) * SEQ + kn + 64];
        }

#pragma unroll
        for (int half = 0; half < 2; ++half) {
            const int k0 = tt * 128 + half * 64;
            const float mb0 = mbp[k0 + l31];
            const float mb1 = mbp[k0 + 32 + l31];
            const ushort_t* Ksc = Ks[half];
            const ushort_t* Vsc = Vs[half];

            // ---- S = Q K^T : two 32x32 key-blocks, K dim = 64 (4 x 16) ----
            f32x16 sacc0 = zero16(), sacc1 = zero16();
            __builtin_amdgcn_s_setprio(1);
#pragma unroll
            for (int ks = 0; ks < 4; ++ks) {
                s16x8 kf0 = *(const s16x8*)&Ksc[(l31)      * 72 + ks * 16 + lh * 8];
                s16x8 kf1 = *(const s16x8*)&Ksc[(32 + l31) * 72 + ks * 16 + lh * 8];
                sacc0 = __builtin_amdgcn_mfma_f32_32x32x16_bf16(qf[ks], kf0, sacc0, 0, 0, 0);
                sacc1 = __builtin_amdgcn_mfma_f32_32x32x16_bf16(qf[ks], kf1, sacc1, 0, 0, 0);
            }
            __builtin_amdgcn_s_setprio(0);

            // ---- P = exp2(S*CSC + maskbias), bf16 scalar stores to Ps ----
#pragma unroll
            for (int rp = 0; rp < 8; ++rp) {
                const int r0 = 2 * rp;
                const int rowb = (r0 & 3) + 8 * (r0 >> 2) + 4 * lh;
                float p0 = __builtin_amdgcn_exp2f(fmaf(sacc0[r0],     CSC, mb0));
                float p1 = __builtin_amdgcn_exp2f(fmaf(sacc0[r0 + 1], CSC, mb0));
                float p2 = __builtin_amdgcn_exp2f(fmaf(sacc1[r0],     CSC, mb1));
                float p3 = __builtin_amdgcn_exp2f(fmaf(sacc1[r0 + 1], CSC, mb1));
                lpart[r0]     += p0 + p2;
                lpart[r0 + 1] += p1 + p3;
                unsigned ua = cvt_pk_bf16(p0, p1);
                unsigned ub = cvt_pk_bf16(p2, p3);
                int base0 = (prow + rowb) * 72 + l31;
                Ps[base0]           = (ushort_t)ua;
                Ps[base0 + 72]      = (ushort_t)(ua >> 16);
                Ps[base0 + 32]      = (ushort_t)ub;
                Ps[base0 + 72 + 32] = (ushort_t)(ub >> 16);
            }
            __builtin_amdgcn_sched_barrier(0);   // pin P-stores before PV reads

            // ---- O += P V : A = Ps rows (q), B = Vs rows (V^T, d) ----
            __builtin_amdgcn_s_setprio(1);
#pragma unroll
            for (int ks = 0; ks < 4; ++ks) {
                s16x8 pa  = *(const s16x8*)&Ps[(prow + l31) * 72 + ks * 16 + lh * 8];
                s16x8 vf0 = *(const s16x8*)&Vsc[(l31)      * 72 + ks * 16 + lh * 8];
                s16x8 vf1 = *(const s16x8*)&Vsc[(32 + l31) * 72 + ks * 16 + lh * 8];
                oacc0 = __builtin_amdgcn_mfma_f32_32x32x16_bf16(pa, vf0, oacc0, 0, 0, 0);
                oacc1 = __builtin_amdgcn_mfma_f32_32x32x16_bf16(pa, vf1, oacc1, 0, 0, 0);
            }
            __builtin_amdgcn_s_setprio(0);
        }
    }

    // ---- epilogue: reduce row sums over the 32-lane half, normalize, store ----
#pragma unroll
    for (int rg = 0; rg < 16; ++rg) {
        lpart[rg] += __shfl_xor(lpart[rg], 1);
        lpart[rg] += __shfl_xor(lpart[rg], 2);
        lpart[rg] += __shfl_xor(lpart[rg], 4);
        lpart[rg] += __shfl_xor(lpart[rg], 8);
        lpart[rg] += __shfl_xor(lpart[rg], 16);   // stays within the 32-lane half
    }
    const size_t obase = ((size_t)b * SEQ + q0 + w * 32) * D_MODEL + h * DKH + l31;
#pragma unroll
    for (int rg = 0; rg < 16; ++rg) {
        const int qrow = (rg & 3) + 8 * (rg >> 2) + 4 * lh;
        const float inv = 1.f / lpart[rg];
        Ctx[obase + (size_t)qrow * D_MODEL]      = f2bf(oacc0[rg] * inv);
        Ctx[obase + (size_t)qrow * D_MODEL + 32] = f2bf(oacc1[rg] * inv);
    }
}

extern "C" void kernel_launch(void* const* d_in, const int* in_sizes, int n_in,
                              void* d_out, int out_size, void* d_ws, size_t ws_size,
                              hipStream_t stream) {
    const float* q    = (const float*)d_in[0];
    const float* k    = (const float*)d_in[1];
    const float* v    = (const float*)d_in[2];
    const int*   mask = (const int*)  d_in[3];
    const float* Wq   = (const float*)d_in[4];
    const float* bq   = (const float*)d_in[5];
    const float* Wk   = (const float*)d_in[6];
    const float* bk   = (const float*)d_in[7];
    const float* Wv   = (const float*)d_in[8];
    const float* bv   = (const float*)d_in[9];
    const float* Wo   = (const float*)d_in[10];
    const float* bo   = (const float*)d_in[11];
    float* out = (float*)d_out;

    char* ws = (char*)d_ws;
    ushort_t* Wqb  = (ushort_t*)(ws);                 //  0- 2 MB
    ushort_t* Wkb  = (ushort_t*)(ws + ( 2u << 20));   //  2- 4
    ushort_t* Wvb  = (ushort_t*)(ws + ( 4u << 20));   //  4- 6
    ushort_t* Wohi = (ushort_t*)(ws + ( 6u << 20));   //  6- 8
    ushort_t* Wolo = (ushort_t*)(ws + ( 8u << 20));   //  8-10
    float*    mb   = (float*)   (ws + (10u << 20));   // 10-12 (16KB used)
    ushort_t* qb   = (ushort_t*)(ws + (12u << 20));   // 12-20
    ushort_t* kb   = (ushort_t*)(ws + (20u << 20));   // 20-28
    ushort_t* vb   = (ushort_t*)(ws + (28u << 20));   // 28-36
    ushort_t* Qb   = (ushort_t*)(ws + (36u << 20));   // 36-44
    ushort_t* Kb   = (ushort_t*)(ws + (44u << 20));   // 44-52
    ushort_t* Vtb  = (ushort_t*)(ws + (52u << 20));   // 52-60
    ushort_t* Ctx  = qb;   // alias: qb free after gemm_qkv consumes it

    convert_all<<<2048, 256, 0, stream>>>(q, k, v, Wq, Wk, Wv, Wo, mask,
                                          qb, kb, vb, Wqb, Wkb, Wvb,
                                          Wohi, Wolo, mb);

    dim3 qkvgrid(D_MODEL / 128, TOK / 128, 3);
    gemm_qkv<<<qkvgrid, 256, 0, stream>>>(qb, kb, vb, Wqb, Wkb, Wvb,
                                          bq, bk, bv, Qb, Kb, Vtb);

    dim3 agrid(BATCH * NHEAD, SEQ / 128);   // x=bh -> XCD-local K/V reuse
    flash7<<<agrid, 256, 0, stream>>>(Qb, Kb, Vtb, mb, Ctx);

    dim3 ogrid(D_MODEL / 64, TOK / 128);
    gemm_out<<<ogrid, 256, 0, stream>>>(Ctx, Wohi, Wolo, bo, out);
}

// Round 18
// 155.481 us; speedup vs baseline: 1.2189x; 1.2189x over previous
//
#include <hip/hip_runtime.h>
#include <math.h>

#define D_MODEL 1024
#define NHEAD   16
#define DKH     64
#define SEQ     2048
#define BATCH   2
#define TOK     (BATCH*SEQ)   // 4096

typedef short s16x8 __attribute__((ext_vector_type(8)));
typedef float f32x4 __attribute__((ext_vector_type(4)));
typedef float f32x16 __attribute__((ext_vector_type(16)));
typedef unsigned short ushort_t;

__device__ inline unsigned short f2bf(float f) {
    union { float f; unsigned u; } v; v.f = f;
    unsigned r = v.u + 0x7FFFu + ((v.u >> 16) & 1u);   // RNE
    return (unsigned short)(r >> 16);
}
__device__ inline float bf2f(ushort_t h) {
    union { unsigned u; float f; } v; v.u = (unsigned)h << 16;
    return v.f;
}
__device__ inline unsigned cvt_pk_bf16(float a, float b) {  // low16=bf16(a), high16=bf16(b)
    unsigned r;
    asm("v_cvt_pk_bf16_f32 %0, %1, %2" : "=v"(r) : "v"(a), "v"(b));
    return r;
}
__device__ inline void gload16(const void* g, void* l) {
    __builtin_amdgcn_global_load_lds(
        (const __attribute__((address_space(1))) void*)g,
        (__attribute__((address_space(3))) void*)l, 16, 0, 0);
}
__device__ inline f32x16 zero16() {
    f32x16 v;
#pragma unroll
    for (int i = 0; i < 16; ++i) v[i] = 0.f;
    return v;
}

// ---------------------------------------------------------------------------
// fp32->bf16: q,k,v and Wq,Wk,Wv plain; Wo as hi+lo split; mask -> float bias.
// ---------------------------------------------------------------------------
__global__ __launch_bounds__(256) void convert_all(
    const float* __restrict__ q, const float* __restrict__ k,
    const float* __restrict__ v,
    const float* __restrict__ Wq, const float* __restrict__ Wk,
    const float* __restrict__ Wv, const float* __restrict__ Wo,
    const int* __restrict__ mask,
    ushort_t* __restrict__ qb, ushort_t* __restrict__ kb,
    ushort_t* __restrict__ vb,
    ushort_t* __restrict__ Wqb, ushort_t* __restrict__ Wkb,
    ushort_t* __restrict__ Wvb, ushort_t* __restrict__ Wohi,
    ushort_t* __restrict__ Wolo, float* __restrict__ mb)
{
    const int ACT4 = TOK * D_MODEL / 4;       // 1048576
    const int W4   = D_MODEL * D_MODEL / 4;   // 262144
    const int total = 3 * ACT4 + 4 * W4 + TOK / 4;
    for (int u = blockIdx.x * 256 + threadIdx.x; u < total; u += gridDim.x * 256) {
        if (u < 3 * ACT4) {
            int which = u / ACT4, off = u - which * ACT4;
            const float* src = which == 0 ? q : which == 1 ? k : v;
            ushort_t*    dst = which == 0 ? qb : which == 1 ? kb : vb;
            float4 f = ((const float4*)src)[off];
            uint2 o;
            o.x = cvt_pk_bf16(f.x, f.y);
            o.y = cvt_pk_bf16(f.z, f.w);
            ((uint2*)dst)[off] = o;
        } else if (u < 3 * ACT4 + 3 * W4) {
            int uu = u - 3 * ACT4;
            int which = uu / W4, off = uu - which * W4;
            const float* src = which == 0 ? Wq : which == 1 ? Wk : Wv;
            ushort_t*    dst = which == 0 ? Wqb : which == 1 ? Wkb : Wvb;
            float4 f = ((const float4*)src)[off];
            uint2 o;
            o.x = cvt_pk_bf16(f.x, f.y);
            o.y = cvt_pk_bf16(f.z, f.w);
            ((uint2*)dst)[off] = o;
        } else if (u < 3 * ACT4 + 4 * W4) {
            int off = u - (3 * ACT4 + 3 * W4);
            float4 f = ((const float4*)Wo)[off];
            ushort_t h0 = f2bf(f.x), h1 = f2bf(f.y), h2 = f2bf(f.z), h3 = f2bf(f.w);
            uint2 hw;
            hw.x = (unsigned)h0 | ((unsigned)h1 << 16);
            hw.y = (unsigned)h2 | ((unsigned)h3 << 16);
            ((uint2*)Wohi)[off] = hw;
            uint2 lw;
            lw.x = cvt_pk_bf16(f.x - bf2f(h0), f.y - bf2f(h1));
            lw.y = cvt_pk_bf16(f.z - bf2f(h2), f.w - bf2f(h3));
            ((uint2*)Wolo)[off] = lw;
        } else {
            int off = u - (3 * ACT4 + 4 * W4);
            int4 m = ((const int4*)mask)[off];
            float4 f;
            f.x = m.x ? 0.f : -1e9f;
            f.y = m.y ? 0.f : -1e9f;
            f.z = m.z ? 0.f : -1e9f;
            f.w = m.w ? 0.f : -1e9f;
            ((float4*)mb)[off] = f;
        }
    }
}

// ---------------------------------------------------------------------------
// Fused Q/K/V projection GEMM, pure bf16 (m97 structure): blockIdx.z = {q,k,v}.
// BM=128 BN=128 BK=32, 256 thr, wave-tile 64x64, global_load_lds staging,
// chunked XCD swizzle. z<2 -> row-major bf16; z==2 -> [b][h][d][s].
// ---------------------------------------------------------------------------
__global__ __launch_bounds__(256) void gemm_qkv(
    const ushort_t* __restrict__ qb, const ushort_t* __restrict__ kb,
    const ushort_t* __restrict__ vb,
    const ushort_t* __restrict__ Wqb, const ushort_t* __restrict__ Wkb,
    const ushort_t* __restrict__ Wvb,
    const float* __restrict__ bqp, const float* __restrict__ bkp,
    const float* __restrict__ bvp,
    ushort_t* __restrict__ Qb, ushort_t* __restrict__ Kb,
    ushort_t* __restrict__ Vtb)
{
    __shared__ __align__(16) char pool[64 * 136 * 2];   // 16KB staging / 17KB epi
    ushort_t* As = (ushort_t*)pool;                     // [128][32]
    ushort_t* Ws = As + 128 * 32;                       // [128][32]

    const int z = blockIdx.z;
    const ushort_t* Ain  = z == 0 ? qb : z == 1 ? kb : vb;
    const ushort_t* Wptr = z == 0 ? Wqb : z == 1 ? Wkb : Wvb;
    const float*    bias = z == 0 ? bqp : z == 1 ? bkp : bvp;

    const int hwid = blockIdx.x + 8 * blockIdx.y;       // 0..255, XCD = hwid%8
    const int work = (hwid & 7) * 32 + (hwid >> 3);
    const int m0 = (work >> 3) * 128;
    const int n0 = (work & 7) * 128;

    const int t = threadIdx.x;
    const int w = t >> 6, lane = t & 63, l15 = lane & 15, l4 = lane >> 4;
    const int wr = w >> 1, wc = w & 1;

    f32x4 acc[4][4];
#pragma unroll
    for (int m = 0; m < 4; ++m)
#pragma unroll
        for (int n = 0; n < 4; ++n) acc[m][n] = (f32x4){0.f, 0.f, 0.f, 0.f};

    const ushort_t* Ag = Ain  + (size_t)(m0 + (t >> 2)) * D_MODEL + (t & 3) * 8;
    const ushort_t* Wg = Wptr + (size_t)(n0 + (t >> 2)) * D_MODEL + (t & 3) * 8;
    ushort_t* AsW = As + w * 512;
    ushort_t* WsW = Ws + w * 512;

    for (int k0 = 0; k0 < D_MODEL; k0 += 32) {
        __syncthreads();
        gload16(Ag + k0, AsW);
        gload16(Ag + (size_t)64 * D_MODEL + k0, AsW + 2048);
        gload16(Wg + k0, WsW);
        gload16(Wg + (size_t)64 * D_MODEL + k0, WsW + 2048);
        __syncthreads();

        s16x8 af[4], bfr[4];
#pragma unroll
        for (int m = 0; m < 4; ++m)
            af[m] = *(const s16x8*)&As[(wr * 64 + m * 16 + l15) * 32 + l4 * 8];
#pragma unroll
        for (int n = 0; n < 4; ++n)
            bfr[n] = *(const s16x8*)&Ws[(wc * 64 + n * 16 + l15) * 32 + l4 * 8];
#pragma unroll
        for (int m = 0; m < 4; ++m)
#pragma unroll
            for (int n = 0; n < 4; ++n)
                acc[m][n] = __builtin_amdgcn_mfma_f32_16x16x32_bf16(af[m], bfr[n], acc[m][n], 0, 0, 0);
    }

    if (z == 2) {   // transposed per-head epilogue -> Vtb[b][h][d][s], 2 halves
        ushort_t* Ct = (ushort_t*)pool;   // [64][136]
        const int h0 = n0 >> 6;
        const int bb = m0 >> 11;
        const int s0 = m0 & (SEQ - 1);
#pragma unroll
        for (int hh = 0; hh < 2; ++hh) {
            __syncthreads();
            if (wc == hh) {
#pragma unroll
                for (int n = 0; n < 4; ++n) {
                    const int nl = n * 16 + l15;
                    const float bv = bias[n0 + hh * 64 + nl];
#pragma unroll
                    for (int m = 0; m < 4; ++m) {
                        const int ml = wr * 64 + m * 16 + l4 * 4;
#pragma unroll
                        for (int r = 0; r < 4; ++r)
                            Ct[nl * 136 + ml + r] = f2bf(acc[m][n][r] + bv);
                    }
                }
            }
            __syncthreads();
            const int dl = t >> 2;
            ushort_t* dst = Vtb + (((size_t)bb * NHEAD + h0 + hh) * DKH + dl) * SEQ + s0;
#pragma unroll
            for (int c = 0; c < 4; ++c) {
                int chk = (t & 3) + c * 4;
                *(uint4*)&dst[chk * 8] = *(const uint4*)&Ct[dl * 136 + chk * 8];
            }
        }
    } else {
        ushort_t* Cout = z == 0 ? Qb : Kb;
#pragma unroll
        for (int n = 0; n < 4; ++n) {
            const int col = n0 + wc * 64 + n * 16 + l15;
            const float bv = bias[col];
#pragma unroll
            for (int m = 0; m < 4; ++m) {
                const int row = m0 + wr * 64 + m * 16 + l4 * 4;
#pragma unroll
                for (int r = 0; r < 4; ++r)
                    Cout[(size_t)(row + r) * D_MODEL + col] = f2bf(acc[m][n][r] + bv);
            }
        }
    }
}

// ---------------------------------------------------------------------------
// Output projection GEMM: C[TOK][D] fp32 = Ctx_bf16 @ (Wohi + Wolo)^T + bias.
// BM=128 BN=64 BK=32, 256 thr, global_load_lds staging + chunked XCD swizzle.
// ---------------------------------------------------------------------------
__global__ __launch_bounds__(256) void gemm_out(
    const ushort_t* __restrict__ Ain, const ushort_t* __restrict__ Wptr,
    const ushort_t* __restrict__ W2ptr, const float* __restrict__ bias,
    float* __restrict__ Cout)
{
    __shared__ ushort_t As[128 * 32];
    __shared__ ushort_t Ws[64 * 32];
    __shared__ ushort_t Ws2[64 * 32];

    const int hwid = blockIdx.x + 16 * blockIdx.y;
    const int work = (hwid & 7) * 64 + (hwid >> 3);
    const int m0 = (work >> 4) * 128;
    const int n0 = (work & 15) * 64;

    const int t = threadIdx.x;
    const int w = t >> 6, lane = t & 63, l15 = lane & 15, l4 = lane >> 4;
    const int wr = w >> 1, wc = w & 1;

    f32x4 acc[4][2];
#pragma unroll
    for (int m = 0; m < 4; ++m)
#pragma unroll
        for (int n = 0; n < 2; ++n) acc[m][n] = (f32x4){0.f, 0.f, 0.f, 0.f};

    const ushort_t* Ag  = Ain   + (size_t)(m0 + (t >> 2)) * D_MODEL + (t & 3) * 8;
    const ushort_t* Wg  = Wptr  + (size_t)(n0 + (t >> 2)) * D_MODEL + (t & 3) * 8;
    const ushort_t* W2g = W2ptr + (size_t)(n0 + (t >> 2)) * D_MODEL + (t & 3) * 8;
    ushort_t* AsW = As + w * 512;
    ushort_t* WsW = Ws + w * 512;
    ushort_t* Ws2W = Ws2 + w * 512;

    for (int k0 = 0; k0 < D_MODEL; k0 += 32) {
        __syncthreads();
        gload16(Ag + k0, AsW);
        gload16(Ag + (size_t)64 * D_MODEL + k0, AsW + 2048);
        gload16(Wg + k0, WsW);
        gload16(W2g + k0, Ws2W);
        __syncthreads();

        s16x8 af[4], bfr[2], bfr2[2];
#pragma unroll
        for (int m = 0; m < 4; ++m)
            af[m] = *(const s16x8*)&As[(wr * 64 + m * 16 + l15) * 32 + l4 * 8];
#pragma unroll
        for (int n = 0; n < 2; ++n) {
            bfr[n]  = *(const s16x8*)&Ws[(wc * 32 + n * 16 + l15) * 32 + l4 * 8];
            bfr2[n] = *(const s16x8*)&Ws2[(wc * 32 + n * 16 + l15) * 32 + l4 * 8];
        }
#pragma unroll
        for (int m = 0; m < 4; ++m)
#pragma unroll
            for (int n = 0; n < 2; ++n) {
                acc[m][n] = __builtin_amdgcn_mfma_f32_16x16x32_bf16(af[m], bfr[n],  acc[m][n], 0, 0, 0);
                acc[m][n] = __builtin_amdgcn_mfma_f32_16x16x32_bf16(af[m], bfr2[n], acc[m][n], 0, 0, 0);
            }
    }

#pragma unroll
    for (int n = 0; n < 2; ++n) {
        const int col = n0 + wc * 32 + n * 16 + l15;
        const float bv = bias[col];
#pragma unroll
        for (int m = 0; m < 4; ++m) {
            const int row = m0 + wr * 64 + m * 16 + l4 * 4;
#pragma unroll
            for (int r = 0; r < 4; ++r)
                Cout[(size_t)(row + r) * D_MODEL + col] = acc[m][n][r] + bv;
        }
    }
}

// ---------------------------------------------------------------------------
// Flash attention v8: flash5 body (PASSED round 15), split-K over the KV axis.
// blockIdx.z in {0,1} selects a 1024-key half. The no-max softmax makes
// partials exactly additive: O_unnorm and l just add across halves.
// Body (staging, LDS geometry, MFMA, P path, setprio) byte-identical to
// flash5; only the loop range and the epilogue differ (no normalize; write
// bf16 unnormalized O + per-(row,head) l). Grid doubles -> 4 blocks/CU.
// ---------------------------------------------------------------------------
__global__ __launch_bounds__(256) void flash8(
    const ushort_t* __restrict__ Q, const ushort_t* __restrict__ K,
    const ushort_t* __restrict__ Vt, const float* __restrict__ mb,
    ushort_t* __restrict__ O0, ushort_t* __restrict__ O1,
    float* __restrict__ Lp)
{
    __shared__ ushort_t Ks[64 * 72];
    __shared__ ushort_t Vs[64 * 72];
    __shared__ ushort_t Ps[128 * 72];

    const int t = threadIdx.x;
    const int w = t >> 6, lane = t & 63;
    const int l31 = lane & 31, lh = lane >> 5;
    const int q0 = blockIdx.y * 128;
    const int bh = blockIdx.x, b = bh >> 4, h = bh & 15;
    const int z  = blockIdx.z;
    const int kbase = z * (SEQ / 2);   // 0 or 1024

    s16x8 qf[4];
    {
        const ushort_t* qp = Q + ((size_t)b * SEQ + q0 + w * 32 + l31) * D_MODEL + h * DKH + lh * 8;
#pragma unroll
        for (int ks = 0; ks < 4; ++ks)
            qf[ks] = *(const s16x8*)(qp + ks * 16);
    }

    f32x16 oacc0 = zero16(), oacc1 = zero16();
    float lpart[16];
#pragma unroll
    for (int i = 0; i < 16; ++i) lpart[i] = 0.f;

    const int ch   = t & 7;
    const int row0 = t >> 3;
    const ushort_t* Kg = K  + ((size_t)b * SEQ) * D_MODEL + h * DKH + ch * 8;
    const ushort_t* Vg = Vt + ((size_t)bh * DKH) * SEQ + ch * 8;

    uint4 kr0 = *(const uint4*)&Kg[(size_t)(kbase + row0) * D_MODEL];
    uint4 kr1 = *(const uint4*)&Kg[(size_t)(kbase + row0 + 32) * D_MODEL];
    uint4 vr0 = *(const uint4*)&Vg[(size_t)row0 * SEQ + kbase];
    uint4 vr1 = *(const uint4*)&Vg[(size_t)(row0 + 32) * SEQ + kbase];

    const float CSC = 0.18033688011112042f;   // 0.125 * log2(e)
    const float* mbp = mb + b * SEQ;
    const int prow = w * 32;                  // wave's private Ps row base

    const int kend = kbase + SEQ / 2;
    for (int k0 = kbase; k0 < kend; k0 += 64) {
        __syncthreads();
        *(uint4*)&Ks[row0 * 72 + ch * 8]        = kr0;
        *(uint4*)&Ks[(row0 + 32) * 72 + ch * 8] = kr1;
        *(uint4*)&Vs[row0 * 72 + ch * 8]        = vr0;
        *(uint4*)&Vs[(row0 + 32) * 72 + ch * 8] = vr1;
        __syncthreads();
        if (k0 + 64 < kend) {
            kr0 = *(const uint4*)&Kg[(size_t)(k0 + 64 + row0) * D_MODEL];
            kr1 = *(const uint4*)&Kg[(size_t)(k0 + 64 + row0 + 32) * D_MODEL];
            vr0 = *(const uint4*)&Vg[(size_t)row0 * SEQ + k0 + 64];
            vr1 = *(const uint4*)&Vg[(size_t)(row0 + 32) * SEQ + k0 + 64];
        }
        const float mb0 = mbp[k0 + l31];
        const float mb1 = mbp[k0 + 32 + l31];

        // ---- S = Q K^T : two 32x32 key-blocks, K dim = 64 (4 x 16) ----
        f32x16 sacc0 = zero16(), sacc1 = zero16();
        __builtin_amdgcn_s_setprio(1);
#pragma unroll
        for (int ks = 0; ks < 4; ++ks) {
            s16x8 kf0 = *(const s16x8*)&Ks[(l31)      * 72 + ks * 16 + lh * 8];
            s16x8 kf1 = *(const s16x8*)&Ks[(32 + l31) * 72 + ks * 16 + lh * 8];
            sacc0 = __builtin_amdgcn_mfma_f32_32x32x16_bf16(qf[ks], kf0, sacc0, 0, 0, 0);
            sacc1 = __builtin_amdgcn_mfma_f32_32x32x16_bf16(qf[ks], kf1, sacc1, 0, 0, 0);
        }
        __builtin_amdgcn_s_setprio(0);

        // ---- P = exp2(S*CSC + maskbias), bf16 scalar stores to Ps[q][key] ----
#pragma unroll
        for (int rp = 0; rp < 8; ++rp) {
            const int r0 = 2 * rp;
            const int rowb = (r0 & 3) + 8 * (r0 >> 2) + 4 * lh;
            float p0 = __builtin_amdgcn_exp2f(fmaf(sacc0[r0],     CSC, mb0));
            float p1 = __builtin_amdgcn_exp2f(fmaf(sacc0[r0 + 1], CSC, mb0));
            float p2 = __builtin_amdgcn_exp2f(fmaf(sacc1[r0],     CSC, mb1));
            float p3 = __builtin_amdgcn_exp2f(fmaf(sacc1[r0 + 1], CSC, mb1));
            lpart[r0]     += p0 + p2;
            lpart[r0 + 1] += p1 + p3;
            unsigned ua = cvt_pk_bf16(p0, p1);
            unsigned ub = cvt_pk_bf16(p2, p3);
            int base0 = (prow + rowb) * 72 + l31;
            Ps[base0]           = (ushort_t)ua;
            Ps[base0 + 72]      = (ushort_t)(ua >> 16);
            Ps[base0 + 32]      = (ushort_t)ub;
            Ps[base0 + 72 + 32] = (ushort_t)(ub >> 16);
        }
        __builtin_amdgcn_sched_barrier(0);   // pin P-stores before PV reads

        // ---- O += P V : A = Ps rows (q), B = Vs rows (V^T, d) ----
        __builtin_amdgcn_s_setprio(1);
#pragma unroll
        for (int ks = 0; ks < 4; ++ks) {
            s16x8 pa  = *(const s16x8*)&Ps[(prow + l31) * 72 + ks * 16 + lh * 8];
            s16x8 vf0 = *(const s16x8*)&Vs[(l31)      * 72 + ks * 16 + lh * 8];
            s16x8 vf1 = *(const s16x8*)&Vs[(32 + l31) * 72 + ks * 16 + lh * 8];
            oacc0 = __builtin_amdgcn_mfma_f32_32x32x16_bf16(pa, vf0, oacc0, 0, 0, 0);
            oacc1 = __builtin_amdgcn_mfma_f32_32x32x16_bf16(pa, vf1, oacc1, 0, 0, 0);
        }
        __builtin_amdgcn_s_setprio(0);
    }

    // ---- epilogue: reduce row sums; write UNNORMALIZED bf16 O + l ----
#pragma unroll
    for (int rg = 0; rg < 16; ++rg) {
        lpart[rg] += __shfl_xor(lpart[rg], 1);
        lpart[rg] += __shfl_xor(lpart[rg], 2);
        lpart[rg] += __shfl_xor(lpart[rg], 4);
        lpart[rg] += __shfl_xor(lpart[rg], 8);
        lpart[rg] += __shfl_xor(lpart[rg], 16);   // stays within the 32-lane half
    }
    ushort_t* Op = z == 0 ? O0 : O1;
    float* lp = Lp + (size_t)z * TOK * NHEAD;
    const size_t obase = ((size_t)b * SEQ + q0 + w * 32) * D_MODEL + h * DKH + l31;
#pragma unroll
    for (int rg = 0; rg < 16; ++rg) {
        const int qrow = (rg & 3) + 8 * (rg >> 2) + 4 * lh;
        Op[obase + (size_t)qrow * D_MODEL]      = f2bf(oacc0[rg]);
        Op[obase + (size_t)qrow * D_MODEL + 32] = f2bf(oacc1[rg]);
        if (l31 == 0)
            lp[((size_t)b * SEQ + q0 + w * 32 + qrow) * NHEAD + h] = lpart[rg];
    }
}

// ---------------------------------------------------------------------------
// Combine: ctx = (O0 + O1) / (l0 + l1), bf16 out. 8 elems/thread (same head).
// ---------------------------------------------------------------------------
__global__ __launch_bounds__(256) void combine(
    const ushort_t* __restrict__ O0, const ushort_t* __restrict__ O1,
    const float* __restrict__ Lp, ushort_t* __restrict__ Ctx)
{
    const int idx = blockIdx.x * 256 + threadIdx.x;    // chunk of 8 bf16
    const int e   = idx * 8;
    const int row = e >> 10;            // / D_MODEL
    const int h   = (e & (D_MODEL - 1)) >> 6;
    const float l0 = Lp[(size_t)row * NHEAD + h];
    const float l1 = Lp[(size_t)TOK * NHEAD + (size_t)row * NHEAD + h];
    const float inv = 1.f / (l0 + l1);
    uint4 a = ((const uint4*)O0)[idx];
    uint4 c = ((const uint4*)O1)[idx];
    const unsigned* au = (const unsigned*)&a;
    const unsigned* cu = (const unsigned*)&c;
    uint4 o;
    unsigned* ou = (unsigned*)&o;
#pragma unroll
    for (int j = 0; j < 4; ++j) {
        float x0 = bf2f((ushort_t)(au[j] & 0xffff)) + bf2f((ushort_t)(cu[j] & 0xffff));
        float x1 = bf2f((ushort_t)(au[j] >> 16))    + bf2f((ushort_t)(cu[j] >> 16));
        ou[j] = cvt_pk_bf16(x0 * inv, x1 * inv);
    }
    ((uint4*)Ctx)[idx] = o;
}

extern "C" void kernel_launch(void* const* d_in, const int* in_sizes, int n_in,
                              void* d_out, int out_size, void* d_ws, size_t ws_size,
                              hipStream_t stream) {
    const float* q    = (const float*)d_in[0];
    const float* k    = (const float*)d_in[1];
    const float* v    = (const float*)d_in[2];
    const int*   mask = (const int*)  d_in[3];
    const float* Wq   = (const float*)d_in[4];
    const float* bq   = (const float*)d_in[5];
    const float* Wk   = (const float*)d_in[6];
    const float* bk   = (const float*)d_in[7];
    const float* Wv   = (const float*)d_in[8];
    const float* bv   = (const float*)d_in[9];
    const float* Wo   = (const float*)d_in[10];
    const float* bo   = (const float*)d_in[11];
    float* out = (float*)d_out;

    char* ws = (char*)d_ws;
    ushort_t* Wqb  = (ushort_t*)(ws);                 //  0- 2 MB
    ushort_t* Wkb  = (ushort_t*)(ws + ( 2u << 20));   //  2- 4
    ushort_t* Wvb  = (ushort_t*)(ws + ( 4u << 20));   //  4- 6
    ushort_t* Wohi = (ushort_t*)(ws + ( 6u << 20));   //  6- 8
    ushort_t* Wolo = (ushort_t*)(ws + ( 8u << 20));   //  8-10
    float*    mb   = (float*)   (ws + (10u << 20));   // 10-11 (16KB used)
    float*    Lp   = (float*)   (ws + (11u << 20));   // 11-12 (512KB used)
    ushort_t* qb   = (ushort_t*)(ws + (12u << 20));   // 12-20
    ushort_t* kb   = (ushort_t*)(ws + (20u << 20));   // 20-28
    ushort_t* vb   = (ushort_t*)(ws + (28u << 20));   // 28-36
    ushort_t* Qb   = (ushort_t*)(ws + (36u << 20));   // 36-44
    ushort_t* Kb   = (ushort_t*)(ws + (44u << 20));   // 44-52
    ushort_t* Vtb  = (ushort_t*)(ws + (52u << 20));   // 52-60
    ushort_t* Ctx  = qb;   // qb free after gemm_qkv
    ushort_t* O0   = kb;   // kb/vb free after gemm_qkv
    ushort_t* O1   = vb;

    convert_all<<<2048, 256, 0, stream>>>(q, k, v, Wq, Wk, Wv, Wo, mask,
                                          qb, kb, vb, Wqb, Wkb, Wvb,
                                          Wohi, Wolo, mb);

    dim3 qkvgrid(D_MODEL / 128, TOK / 128, 3);
    gemm_qkv<<<qkvgrid, 256, 0, stream>>>(qb, kb, vb, Wqb, Wkb, Wvb,
                                          bq, bk, bv, Qb, Kb, Vtb);

    dim3 agrid(BATCH * NHEAD, SEQ / 128, 2);   // x=bh -> XCD-local K/V reuse
    flash8<<<agrid, 256, 0, stream>>>(Qb, Kb, Vtb, mb, O0, O1, Lp);

    combine<<<TOK * D_MODEL / 8 / 256, 256, 0, stream>>>(O0, O1, Lp, Ctx);

    dim3 ogrid(D_MODEL / 64, TOK / 128);
    gemm_out<<<ogrid, 256, 0, stream>>>(Ctx, Wohi, Wolo, bo, out);
}

// Round 19
// 150.630 us; speedup vs baseline: 1.2582x; 1.0322x over previous
//
#include <hip/hip_runtime.h>
#include <math.h>

#define D_MODEL 1024
#define NHEAD   16
#define DKH     64
#define SEQ     2048
#define BATCH   2
#define TOK     (BATCH*SEQ)   // 4096

typedef short s16x8 __attribute__((ext_vector_type(8)));
typedef float f32x4 __attribute__((ext_vector_type(4)));
typedef float f32x16 __attribute__((ext_vector_type(16)));
typedef unsigned short ushort_t;

__device__ inline unsigned short f2bf(float f) {
    union { float f; unsigned u; } v; v.f = f;
    unsigned r = v.u + 0x7FFFu + ((v.u >> 16) & 1u);   // RNE
    return (unsigned short)(r >> 16);
}
__device__ inline float bf2f(ushort_t h) {
    union { unsigned u; float f; } v; v.u = (unsigned)h << 16;
    return v.f;
}
__device__ inline unsigned cvt_pk_bf16(float a, float b) {  // low16=bf16(a), high16=bf16(b)
    unsigned r;
    asm("v_cvt_pk_bf16_f32 %0, %1, %2" : "=v"(r) : "v"(a), "v"(b));
    return r;
}
__device__ inline void gload16(const void* g, void* l) {
    __builtin_amdgcn_global_load_lds(
        (const __attribute__((address_space(1))) void*)g,
        (__attribute__((address_space(3))) void*)l, 16, 0, 0);
}
__device__ inline f32x16 zero16() {
    f32x16 v;
#pragma unroll
    for (int i = 0; i < 16; ++i) v[i] = 0.f;
    return v;
}

// ---------------------------------------------------------------------------
// fp32->bf16: q,k,v and Wq,Wk,Wv plain; Wo as hi+lo split; mask -> float bias.
// ---------------------------------------------------------------------------
__global__ __launch_bounds__(256) void convert_all(
    const float* __restrict__ q, const float* __restrict__ k,
    const float* __restrict__ v,
    const float* __restrict__ Wq, const float* __restrict__ Wk,
    const float* __restrict__ Wv, const float* __restrict__ Wo,
    const int* __restrict__ mask,
    ushort_t* __restrict__ qb, ushort_t* __restrict__ kb,
    ushort_t* __restrict__ vb,
    ushort_t* __restrict__ Wqb, ushort_t* __restrict__ Wkb,
    ushort_t* __restrict__ Wvb, ushort_t* __restrict__ Wohi,
    ushort_t* __restrict__ Wolo, float* __restrict__ mb)
{
    const int ACT4 = TOK * D_MODEL / 4;       // 1048576
    const int W4   = D_MODEL * D_MODEL / 4;   // 262144
    const int total = 3 * ACT4 + 4 * W4 + TOK / 4;
    for (int u = blockIdx.x * 256 + threadIdx.x; u < total; u += gridDim.x * 256) {
        if (u < 3 * ACT4) {
            int which = u / ACT4, off = u - which * ACT4;
            const float* src = which == 0 ? q : which == 1 ? k : v;
            ushort_t*    dst = which == 0 ? qb : which == 1 ? kb : vb;
            float4 f = ((const float4*)src)[off];
            uint2 o;
            o.x = cvt_pk_bf16(f.x, f.y);
            o.y = cvt_pk_bf16(f.z, f.w);
            ((uint2*)dst)[off] = o;
        } else if (u < 3 * ACT4 + 3 * W4) {
            int uu = u - 3 * ACT4;
            int which = uu / W4, off = uu - which * W4;
            const float* src = which == 0 ? Wq : which == 1 ? Wk : Wv;
            ushort_t*    dst = which == 0 ? Wqb : which == 1 ? Wkb : Wvb;
            float4 f = ((const float4*)src)[off];
            uint2 o;
            o.x = cvt_pk_bf16(f.x, f.y);
            o.y = cvt_pk_bf16(f.z, f.w);
            ((uint2*)dst)[off] = o;
        } else if (u < 3 * ACT4 + 4 * W4) {
            int off = u - (3 * ACT4 + 3 * W4);
            float4 f = ((const float4*)Wo)[off];
            ushort_t h0 = f2bf(f.x), h1 = f2bf(f.y), h2 = f2bf(f.z), h3 = f2bf(f.w);
            uint2 hw;
            hw.x = (unsigned)h0 | ((unsigned)h1 << 16);
            hw.y = (unsigned)h2 | ((unsigned)h3 << 16);
            ((uint2*)Wohi)[off] = hw;
            uint2 lw;
            lw.x = cvt_pk_bf16(f.x - bf2f(h0), f.y - bf2f(h1));
            lw.y = cvt_pk_bf16(f.z - bf2f(h2), f.w - bf2f(h3));
            ((uint2*)Wolo)[off] = lw;
        } else {
            int off = u - (3 * ACT4 + 4 * W4);
            int4 m = ((const int4*)mask)[off];
            float4 f;
            f.x = m.x ? 0.f : -1e9f;
            f.y = m.y ? 0.f : -1e9f;
            f.z = m.z ? 0.f : -1e9f;
            f.w = m.w ? 0.f : -1e9f;
            ((float4*)mb)[off] = f;
        }
    }
}

// ---------------------------------------------------------------------------
// Fused Q/K/V projection GEMM, pure bf16 (m97 structure): blockIdx.z = {q,k,v}.
// BM=128 BN=128 BK=32, 256 thr, wave-tile 64x64, global_load_lds staging,
// chunked XCD swizzle. z<2 -> row-major bf16; z==2 -> [b][h][d][s].
// NEW (T2, rule-#21 recipe): LDS stays LINEAR; the per-lane GLOBAL source
// chunk is XOR-swizzled by (row&3), and fragment reads apply the same XOR
// (l4 ^ (l15&3)). Takes the stride-64B fragment read from 8-way bank
// conflict (2.94x, G4) to 2-way (free). Data in fragments is bit-identical.
// ---------------------------------------------------------------------------
__global__ __launch_bounds__(256) void gemm_qkv(
    const ushort_t* __restrict__ qb, const ushort_t* __restrict__ kb,
    const ushort_t* __restrict__ vb,
    const ushort_t* __restrict__ Wqb, const ushort_t* __restrict__ Wkb,
    const ushort_t* __restrict__ Wvb,
    const float* __restrict__ bqp, const float* __restrict__ bkp,
    const float* __restrict__ bvp,
    ushort_t* __restrict__ Qb, ushort_t* __restrict__ Kb,
    ushort_t* __restrict__ Vtb)
{
    __shared__ __align__(16) char pool[64 * 136 * 2];   // 16KB staging / 17KB epi
    ushort_t* As = (ushort_t*)pool;                     // [128][32] (chunk-swizzled)
    ushort_t* Ws = As + 128 * 32;                       // [128][32]

    const int z = blockIdx.z;
    const ushort_t* Ain  = z == 0 ? qb : z == 1 ? kb : vb;
    const ushort_t* Wptr = z == 0 ? Wqb : z == 1 ? Wkb : Wvb;
    const float*    bias = z == 0 ? bqp : z == 1 ? bkp : bvp;

    const int hwid = blockIdx.x + 8 * blockIdx.y;       // 0..255, XCD = hwid%8
    const int work = (hwid & 7) * 32 + (hwid >> 3);
    const int m0 = (work >> 3) * 128;
    const int n0 = (work & 7) * 128;

    const int t = threadIdx.x;
    const int w = t >> 6, lane = t & 63, l15 = lane & 15, l4 = lane >> 4;
    const int wr = w >> 1, wc = w & 1;

    f32x4 acc[4][4];
#pragma unroll
    for (int m = 0; m < 4; ++m)
#pragma unroll
        for (int n = 0; n < 4; ++n) acc[m][n] = (f32x4){0.f, 0.f, 0.f, 0.f};

    // source pre-swizzle: chunk' = (t&3) ^ ((t>>2)&3); rows +64 keep (row&3)
    const int schunk = (t & 3) ^ ((t >> 2) & 3);
    const ushort_t* Ag = Ain  + (size_t)(m0 + (t >> 2)) * D_MODEL + schunk * 8;
    const ushort_t* Wg = Wptr + (size_t)(n0 + (t >> 2)) * D_MODEL + schunk * 8;
    ushort_t* AsW = As + w * 512;
    ushort_t* WsW = Ws + w * 512;
    const int fx = (l4 ^ (l15 & 3)) * 8;   // swizzled fragment k-offset

    for (int k0 = 0; k0 < D_MODEL; k0 += 32) {
        __syncthreads();
        gload16(Ag + k0, AsW);
        gload16(Ag + (size_t)64 * D_MODEL + k0, AsW + 2048);
        gload16(Wg + k0, WsW);
        gload16(Wg + (size_t)64 * D_MODEL + k0, WsW + 2048);
        __syncthreads();

        s16x8 af[4], bfr[4];
#pragma unroll
        for (int m = 0; m < 4; ++m)
            af[m] = *(const s16x8*)&As[(wr * 64 + m * 16 + l15) * 32 + fx];
#pragma unroll
        for (int n = 0; n < 4; ++n)
            bfr[n] = *(const s16x8*)&Ws[(wc * 64 + n * 16 + l15) * 32 + fx];
#pragma unroll
        for (int m = 0; m < 4; ++m)
#pragma unroll
            for (int n = 0; n < 4; ++n)
                acc[m][n] = __builtin_amdgcn_mfma_f32_16x16x32_bf16(af[m], bfr[n], acc[m][n], 0, 0, 0);
    }

    if (z == 2) {   // transposed per-head epilogue -> Vtb[b][h][d][s], 2 halves
        ushort_t* Ct = (ushort_t*)pool;   // [64][136]
        const int h0 = n0 >> 6;
        const int bb = m0 >> 11;
        const int s0 = m0 & (SEQ - 1);
#pragma unroll
        for (int hh = 0; hh < 2; ++hh) {
            __syncthreads();
            if (wc == hh) {
#pragma unroll
                for (int n = 0; n < 4; ++n) {
                    const int nl = n * 16 + l15;
                    const float bv = bias[n0 + hh * 64 + nl];
#pragma unroll
                    for (int m = 0; m < 4; ++m) {
                        const int ml = wr * 64 + m * 16 + l4 * 4;
#pragma unroll
                        for (int r = 0; r < 4; ++r)
                            Ct[nl * 136 + ml + r] = f2bf(acc[m][n][r] + bv);
                    }
                }
            }
            __syncthreads();
            const int dl = t >> 2;
            ushort_t* dst = Vtb + (((size_t)bb * NHEAD + h0 + hh) * DKH + dl) * SEQ + s0;
#pragma unroll
            for (int c = 0; c < 4; ++c) {
                int chk = (t & 3) + c * 4;
                *(uint4*)&dst[chk * 8] = *(const uint4*)&Ct[dl * 136 + chk * 8];
            }
        }
    } else {
        ushort_t* Cout = z == 0 ? Qb : Kb;
#pragma unroll
        for (int n = 0; n < 4; ++n) {
            const int col = n0 + wc * 64 + n * 16 + l15;
            const float bv = bias[col];
#pragma unroll
            for (int m = 0; m < 4; ++m) {
                const int row = m0 + wr * 64 + m * 16 + l4 * 4;
#pragma unroll
                for (int r = 0; r < 4; ++r)
                    Cout[(size_t)(row + r) * D_MODEL + col] = f2bf(acc[m][n][r] + bv);
            }
        }
    }
}

// ---------------------------------------------------------------------------
// Output projection GEMM: C[TOK][D] fp32 = Ctx_bf16 @ (Wohi + Wolo)^T + bias.
// BM=128 BN=64 BK=32, 256 thr, global_load_lds staging + chunked XCD swizzle.
// Same T2 source-chunk swizzle as gemm_qkv.
// ---------------------------------------------------------------------------
__global__ __launch_bounds__(256) void gemm_out(
    const ushort_t* __restrict__ Ain, const ushort_t* __restrict__ Wptr,
    const ushort_t* __restrict__ W2ptr, const float* __restrict__ bias,
    float* __restrict__ Cout)
{
    __shared__ ushort_t As[128 * 32];
    __shared__ ushort_t Ws[64 * 32];
    __shared__ ushort_t Ws2[64 * 32];

    const int hwid = blockIdx.x + 16 * blockIdx.y;
    const int work = (hwid & 7) * 64 + (hwid >> 3);
    const int m0 = (work >> 4) * 128;
    const int n0 = (work & 15) * 64;

    const int t = threadIdx.x;
    const int w = t >> 6, lane = t & 63, l15 = lane & 15, l4 = lane >> 4;
    const int wr = w >> 1, wc = w & 1;

    f32x4 acc[4][2];
#pragma unroll
    for (int m = 0; m < 4; ++m)
#pragma unroll
        for (int n = 0; n < 2; ++n) acc[m][n] = (f32x4){0.f, 0.f, 0.f, 0.f};

    const int schunk = (t & 3) ^ ((t >> 2) & 3);
    const ushort_t* Ag  = Ain   + (size_t)(m0 + (t >> 2)) * D_MODEL + schunk * 8;
    const ushort_t* Wg  = Wptr  + (size_t)(n0 + (t >> 2)) * D_MODEL + schunk * 8;
    const ushort_t* W2g = W2ptr + (size_t)(n0 + (t >> 2)) * D_MODEL + schunk * 8;
    ushort_t* AsW = As + w * 512;
    ushort_t* WsW = Ws + w * 512;
    ushort_t* Ws2W = Ws2 + w * 512;
    const int fx = (l4 ^ (l15 & 3)) * 8;

    for (int k0 = 0; k0 < D_MODEL; k0 += 32) {
        __syncthreads();
        gload16(Ag + k0, AsW);
        gload16(Ag + (size_t)64 * D_MODEL + k0, AsW + 2048);
        gload16(Wg + k0, WsW);
        gload16(W2g + k0, Ws2W);
        __syncthreads();

        s16x8 af[4], bfr[2], bfr2[2];
#pragma unroll
        for (int m = 0; m < 4; ++m)
            af[m] = *(const s16x8*)&As[(wr * 64 + m * 16 + l15) * 32 + fx];
#pragma unroll
        for (int n = 0; n < 2; ++n) {
            bfr[n]  = *(const s16x8*)&Ws[(wc * 32 + n * 16 + l15) * 32 + fx];
            bfr2[n] = *(const s16x8*)&Ws2[(wc * 32 + n * 16 + l15) * 32 + fx];
        }
#pragma unroll
        for (int m = 0; m < 4; ++m)
#pragma unroll
            for (int n = 0; n < 2; ++n) {
                acc[m][n] = __builtin_amdgcn_mfma_f32_16x16x32_bf16(af[m], bfr[n],  acc[m][n], 0, 0, 0);
                acc[m][n] = __builtin_amdgcn_mfma_f32_16x16x32_bf16(af[m], bfr2[n], acc[m][n], 0, 0, 0);
            }
    }

#pragma unroll
    for (int n = 0; n < 2; ++n) {
        const int col = n0 + wc * 32 + n * 16 + l15;
        const float bv = bias[col];
#pragma unroll
        for (int m = 0; m < 4; ++m) {
            const int row = m0 + wr * 64 + m * 16 + l4 * 4;
#pragma unroll
            for (int r = 0; r < 4; ++r)
                Cout[(size_t)(row + r) * D_MODEL + col] = acc[m][n][r] + bv;
        }
    }
}

// ---------------------------------------------------------------------------
// Flash attention v5 (round-15 VERBATIM, passed at 76us, conflicts=0):
// 32x32x16 MFMA, 4 waves x 32 q-rows, no online max, setprio on MFMA,
// scalar-ushort P stores + sched_barrier(0).
// ---------------------------------------------------------------------------
__global__ __launch_bounds__(256) void flash5(
    const ushort_t* __restrict__ Q, const ushort_t* __restrict__ K,
    const ushort_t* __restrict__ Vt, const float* __restrict__ mb,
    ushort_t* __restrict__ Ctx)
{
    __shared__ ushort_t Ks[64 * 72];
    __shared__ ushort_t Vs[64 * 72];
    __shared__ ushort_t Ps[128 * 72];

    const int t = threadIdx.x;
    const int w = t >> 6, lane = t & 63;
    const int l31 = lane & 31, lh = lane >> 5;
    const int q0 = blockIdx.y * 128;
    const int bh = blockIdx.x, b = bh >> 4, h = bh & 15;

    s16x8 qf[4];
    {
        const ushort_t* qp = Q + ((size_t)b * SEQ + q0 + w * 32 + l31) * D_MODEL + h * DKH + lh * 8;
#pragma unroll
        for (int ks = 0; ks < 4; ++ks)
            qf[ks] = *(const s16x8*)(qp + ks * 16);
    }

    f32x16 oacc0 = zero16(), oacc1 = zero16();
    float lpart[16];
#pragma unroll
    for (int i = 0; i < 16; ++i) lpart[i] = 0.f;

    const int ch   = t & 7;
    const int row0 = t >> 3;
    const ushort_t* Kg = K  + ((size_t)b * SEQ) * D_MODEL + h * DKH + ch * 8;
    const ushort_t* Vg = Vt + ((size_t)bh * DKH) * SEQ + ch * 8;

    uint4 kr0 = *(const uint4*)&Kg[(size_t)row0 * D_MODEL];
    uint4 kr1 = *(const uint4*)&Kg[(size_t)(row0 + 32) * D_MODEL];
    uint4 vr0 = *(const uint4*)&Vg[(size_t)row0 * SEQ];
    uint4 vr1 = *(const uint4*)&Vg[(size_t)(row0 + 32) * SEQ];

    const float CSC = 0.18033688011112042f;   // 0.125 * log2(e)
    const float* mbp = mb + b * SEQ;
    const int prow = w * 32;

    for (int k0 = 0; k0 < SEQ; k0 += 64) {
        __syncthreads();
        *(uint4*)&Ks[row0 * 72 + ch * 8]        = kr0;
        *(uint4*)&Ks[(row0 + 32) * 72 + ch * 8] = kr1;
        *(uint4*)&Vs[row0 * 72 + ch * 8]        = vr0;
        *(uint4*)&Vs[(row0 + 32) * 72 + ch * 8] = vr1;
        __syncthreads();
        if (k0 + 64 < SEQ) {
            kr0 = *(const uint4*)&Kg[(size_t)(k0 + 64 + row0) * D_MODEL];
            kr1 = *(const uint4*)&Kg[(size_t)(k0 + 64 + row0 + 32) * D_MODEL];
            vr0 = *(const uint4*)&Vg[(size_t)row0 * SEQ + k0 + 64];
            vr1 = *(const uint4*)&Vg[(size_t)(row0 + 32) * SEQ + k0 + 64];
        }
        const float mb0 = mbp[k0 + l31];
        const float mb1 = mbp[k0 + 32 + l31];

        f32x16 sacc0 = zero16(), sacc1 = zero16();
        __builtin_amdgcn_s_setprio(1);
#pragma unroll
        for (int ks = 0; ks < 4; ++ks) {
            s16x8 kf0 = *(const s16x8*)&Ks[(l31)      * 72 + ks * 16 + lh * 8];
            s16x8 kf1 = *(const s16x8*)&Ks[(32 + l31) * 72 + ks * 16 + lh * 8];
            sacc0 = __builtin_amdgcn_mfma_f32_32x32x16_bf16(qf[ks], kf0, sacc0, 0, 0, 0);
            sacc1 = __builtin_amdgcn_mfma_f32_32x32x16_bf16(qf[ks], kf1, sacc1, 0, 0, 0);
        }
        __builtin_amdgcn_s_setprio(0);

#pragma unroll
        for (int rp = 0; rp < 8; ++rp) {
            const int r0 = 2 * rp;
            const int rowb = (r0 & 3) + 8 * (r0 >> 2) + 4 * lh;
            float p0 = __builtin_amdgcn_exp2f(fmaf(sacc0[r0],     CSC, mb0));
            float p1 = __builtin_amdgcn_exp2f(fmaf(sacc0[r0 + 1], CSC, mb0));
            float p2 = __builtin_amdgcn_exp2f(fmaf(sacc1[r0],     CSC, mb1));
            float p3 = __builtin_amdgcn_exp2f(fmaf(sacc1[r0 + 1], CSC, mb1));
            lpart[r0]     += p0 + p2;
            lpart[r0 + 1] += p1 + p3;
            unsigned ua = cvt_pk_bf16(p0, p1);
            unsigned ub = cvt_pk_bf16(p2, p3);
            int base0 = (prow + rowb) * 72 + l31;
            Ps[base0]           = (ushort_t)ua;
            Ps[base0 + 72]      = (ushort_t)(ua >> 16);
            Ps[base0 + 32]      = (ushort_t)ub;
            Ps[base0 + 72 + 32] = (ushort_t)(ub >> 16);
        }
        __builtin_amdgcn_sched_barrier(0);

        __builtin_amdgcn_s_setprio(1);
#pragma unroll
        for (int ks = 0; ks < 4; ++ks) {
            s16x8 pa  = *(const s16x8*)&Ps[(prow + l31) * 72 + ks * 16 + lh * 8];
            s16x8 vf0 = *(const s16x8*)&Vs[(l31)      * 72 + ks * 16 + lh * 8];
            s16x8 vf1 = *(const s16x8*)&Vs[(32 + l31) * 72 + ks * 16 + lh * 8];
            oacc0 = __builtin_amdgcn_mfma_f32_32x32x16_bf16(pa, vf0, oacc0, 0, 0, 0);
            oacc1 = __builtin_amdgcn_mfma_f32_32x32x16_bf16(pa, vf1, oacc1, 0, 0, 0);
        }
        __builtin_amdgcn_s_setprio(0);
    }

#pragma unroll
    for (int rg = 0; rg < 16; ++rg) {
        lpart[rg] += __shfl_xor(lpart[rg], 1);
        lpart[rg] += __shfl_xor(lpart[rg], 2);
        lpart[rg] += __shfl_xor(lpart[rg], 4);
        lpart[rg] += __shfl_xor(lpart[rg], 8);
        lpart[rg] += __shfl_xor(lpart[rg], 16);
    }
    const size_t obase = ((size_t)b * SEQ + q0 + w * 32) * D_MODEL + h * DKH + l31;
#pragma unroll
    for (int rg = 0; rg < 16; ++rg) {
        const int qrow = (rg & 3) + 8 * (rg >> 2) + 4 * lh;
        const float inv = 1.f / lpart[rg];
        Ctx[obase + (size_t)qrow * D_MODEL]      = f2bf(oacc0[rg] * inv);
        Ctx[obase + (size_t)qrow * D_MODEL + 32] = f2bf(oacc1[rg] * inv);
    }
}

extern "C" void kernel_launch(void* const* d_in, const int* in_sizes, int n_in,
                              void* d_out, int out_size, void* d_ws, size_t ws_size,
                              hipStream_t stream) {
    const float* q    = (const float*)d_in[0];
    const float* k    = (const float*)d_in[1];
    const float* v    = (const float*)d_in[2];
    const int*   mask = (const int*)  d_in[3];
    const float* Wq   = (const float*)d_in[4];
    const float* bq   = (const float*)d_in[5];
    const float* Wk   = (const float*)d_in[6];
    const float* bk   = (const float*)d_in[7];
    const float* Wv   = (const float*)d_in[8];
    const float* bv   = (const float*)d_in[9];
    const float* Wo   = (const float*)d_in[10];
    const float* bo   = (const float*)d_in[11];
    float* out = (float*)d_out;

    char* ws = (char*)d_ws;
    ushort_t* Wqb  = (ushort_t*)(ws);                 //  0- 2 MB
    ushort_t* Wkb  = (ushort_t*)(ws + ( 2u << 20));   //  2- 4
    ushort_t* Wvb  = (ushort_t*)(ws + ( 4u << 20));   //  4- 6
    ushort_t* Wohi = (ushort_t*)(ws + ( 6u << 20));   //  6- 8
    ushort_t* Wolo = (ushort_t*)(ws + ( 8u << 20));   //  8-10
    float*    mb   = (float*)   (ws + (10u << 20));   // 10-12 (16KB used)
    ushort_t* qb   = (ushort_t*)(ws + (12u << 20));   // 12-20
    ushort_t* kb   = (ushort_t*)(ws + (20u << 20));   // 20-28
    ushort_t* vb   = (ushort_t*)(ws + (28u << 20));   // 28-36
    ushort_t* Qb   = (ushort_t*)(ws + (36u << 20));   // 36-44
    ushort_t* Kb   = (ushort_t*)(ws + (44u << 20));   // 44-52
    ushort_t* Vtb  = (ushort_t*)(ws + (52u << 20));   // 52-60
    ushort_t* Ctx  = qb;   // alias: qb free after gemm_qkv consumes it

    convert_all<<<2048, 256, 0, stream>>>(q, k, v, Wq, Wk, Wv, Wo, mask,
                                          qb, kb, vb, Wqb, Wkb, Wvb,
                                          Wohi, Wolo, mb);

    dim3 qkvgrid(D_MODEL / 128, TOK / 128, 3);
    gemm_qkv<<<qkvgrid, 256, 0, stream>>>(qb, kb, vb, Wqb, Wkb, Wvb,
                                          bq, bk, bv, Qb, Kb, Vtb);

    dim3 agrid(BATCH * NHEAD, SEQ / 128);   // x=bh -> XCD-local K/V reuse
    flash5<<<agrid, 256, 0, stream>>>(Qb, Kb, Vtb, mb, Ctx);

    dim3 ogrid(D_MODEL / 64, TOK / 128);
    gemm_out<<<ogrid, 256, 0, stream>>>(Ctx, Wohi, Wolo, bo, out);
}